// Round 2
// baseline (298.463 us; speedup 1.0000x reference)
//
#include <hip/hip_runtime.h>

#define NNODES 10000
#define F 256
#define H 512

typedef _Float16 half8 __attribute__((ext_vector_type(8)));
typedef _Float16 half4 __attribute__((ext_vector_type(4)));
typedef float floatx4 __attribute__((ext_vector_type(4)));

// ---------- CSR build ----------
__global__ __launch_bounds__(256) void count_k(const int* __restrict__ dst,
                                               int* __restrict__ cnt, int E) {
  int e = blockIdx.x * blockDim.x + threadIdx.x;
  if (e < E) atomicAdd(&cnt[dst[e]], 1);
}

// wave-shuffle scan: 1024 threads, 16 waves, ~4 barriers per 1024-chunk
__global__ __launch_bounds__(1024) void scan_k(const int* __restrict__ cnt,
                                               int* __restrict__ offs,
                                               float* __restrict__ dinv, int N) {
  __shared__ int wsum[16];
  __shared__ int carry_s;
  int tid = threadIdx.x, lane = tid & 63, w = tid >> 6;
  if (tid == 0) carry_s = 0;
  __syncthreads();
  for (int base = 0; base < N; base += 1024) {
    int i = base + tid;
    int v = (i < N) ? cnt[i] : 0;
    int s = v;
    #pragma unroll
    for (int o = 1; o < 64; o <<= 1) {
      int t = __shfl_up(s, o, 64);
      if (lane >= o) s += t;
    }
    if (lane == 63) wsum[w] = s;
    __syncthreads();
    if (w == 0 && lane < 16) {
      int t = wsum[lane];
      #pragma unroll
      for (int o = 1; o < 16; o <<= 1) {
        int u = __shfl_up(t, o, 64);
        if (lane >= o) t += u;
      }
      wsum[lane] = t;  // inclusive wave-sum scan
    }
    __syncthreads();
    int wprefix = (w == 0) ? 0 : wsum[w - 1];
    int carry = carry_s;
    int incl = carry + wprefix + s;
    if (i < N) {
      offs[i] = incl - v;                  // exclusive prefix
      dinv[i] = rsqrtf((float)(v + 1));    // deg includes self-loop
    }
    __syncthreads();
    if (tid == 1023) carry_s = incl;
    __syncthreads();
  }
  if (tid == 0) offs[N] = carry_s;
}

__global__ __launch_bounds__(256) void fill_k(const int* __restrict__ src,
                                              const int* __restrict__ dst,
                                              const int* __restrict__ offs,
                                              int* __restrict__ cursor,
                                              int* __restrict__ csr, int E) {
  int e = blockIdx.x * blockDim.x + threadIdx.x;
  if (e < E) {
    int d = dst[e];
    int p = atomicAdd(&cursor[d], 1);
    csr[offs[d] + p] = src[e];
  }
}

// ---------- weight transpose + f16 convert: W (K x Nc) -> Wt (Nc x K) ----------
__global__ __launch_bounds__(256) void convw_k(const float* __restrict__ W,
                                               _Float16* __restrict__ Wt,
                                               int K, int Nc) {
  int t = blockIdx.x * blockDim.x + threadIdx.x;
  if (t < Nc * K) {
    int n = t / K, k = t - n * K;
    Wt[t] = (_Float16)W[k * Nc + n];
  }
}

// ---------- layer-1 aggregation: 1 wave per node, float4 loads, shfl bcast ----------
__global__ __launch_bounds__(256) void agg1_k(const float* __restrict__ x,
                                              const int* __restrict__ offs,
                                              const int* __restrict__ csr,
                                              const float* __restrict__ dinv,
                                              _Float16* __restrict__ axh, int N) {
  int lane = threadIdx.x & 63;
  int w = threadIdx.x >> 6;
  int nwaves = (gridDim.x * blockDim.x) >> 6;
  int gw = blockIdx.x * (blockDim.x >> 6) + w;
  int f0 = lane * 4;
  for (int node = gw; node < N; node += nwaves) {
    int beg = offs[node], end = offs[node + 1];
    float di = dinv[node];
    floatx4 acc = {0.f, 0.f, 0.f, 0.f};
    for (int c = beg; c < end; c += 64) {
      int m = min(64, end - c);
      int sv = 0; float wv = 0.f;
      if (lane < m) { sv = csr[c + lane]; wv = dinv[sv]; }
      #pragma unroll 4
      for (int j = 0; j < m; j++) {
        int sj = __shfl(sv, j, 64);
        float wj = __shfl(wv, j, 64);
        floatx4 xv = *(const floatx4*)(x + (size_t)sj * F + f0);
        acc += wj * xv;
      }
    }
    floatx4 xs = *(const floatx4*)(x + (size_t)node * F + f0);
    floatx4 tot = di * acc + (di * di) * xs;
    *(half4*)(axh + (size_t)node * F + f0) = __builtin_convertvector(tot, half4);
  }
}

// ---------- GEMM1: (N x 256 f16) @ W1t (512 x 256 f16, n-major) -> relu(+b1) f16 ----------
__global__ __launch_bounds__(256) void gemm1_k(const _Float16* __restrict__ A,
                                               const _Float16* __restrict__ Bt,
                                               const float* __restrict__ bias,
                                               _Float16* __restrict__ Cc) {
  int lane = threadIdx.x & 63;
  int wv = threadIdx.x >> 6;
  int m0 = blockIdx.x * 16;
  int nb = blockIdx.y * 256 + wv * 64;
  int r = lane & 15, q = lane >> 4;
  floatx4 a0 = {0,0,0,0}, a1 = {0,0,0,0}, a2 = {0,0,0,0}, a3 = {0,0,0,0};
  const _Float16* Ap = A + (size_t)(m0 + r) * F + q * 8;
  const _Float16* Bp = Bt + (size_t)(nb + r) * F + q * 8;
  for (int k0 = 0; k0 < F; k0 += 32) {
    half8 a  = *(const half8*)(Ap + k0);
    half8 b0 = *(const half8*)(Bp + k0);
    half8 b1v = *(const half8*)(Bp + 16 * F + k0);
    half8 b2v = *(const half8*)(Bp + 32 * F + k0);
    half8 b3v = *(const half8*)(Bp + 48 * F + k0);
    a0 = __builtin_amdgcn_mfma_f32_16x16x32_f16(a, b0, a0, 0, 0, 0);
    a1 = __builtin_amdgcn_mfma_f32_16x16x32_f16(a, b1v, a1, 0, 0, 0);
    a2 = __builtin_amdgcn_mfma_f32_16x16x32_f16(a, b2v, a2, 0, 0, 0);
    a3 = __builtin_amdgcn_mfma_f32_16x16x32_f16(a, b3v, a3, 0, 0, 0);
  }
  floatx4 accs[4] = {a0, a1, a2, a3};
  #pragma unroll
  for (int nn = 0; nn < 4; nn++) {
    #pragma unroll
    for (int rr = 0; rr < 4; rr++) {
      int row = q * 4 + rr;
      int n = nb + nn * 16 + r;
      float v = accs[nn][rr] + bias[n];
      v = fmaxf(v, 0.f);
      Cc[(size_t)(m0 + row) * H + n] = (_Float16)v;
    }
  }
}

// ---------- GEMM2: (N x 512 f16) @ W2t (256 x 512 f16) -> xw2 f16 (no bias) ----------
__global__ __launch_bounds__(256) void gemm2_k(const _Float16* __restrict__ A,
                                               const _Float16* __restrict__ Bt,
                                               _Float16* __restrict__ Cc) {
  int lane = threadIdx.x & 63;
  int wv = threadIdx.x >> 6;
  int m0 = blockIdx.x * 16;
  int nb = wv * 64;
  int r = lane & 15, q = lane >> 4;
  floatx4 a0 = {0,0,0,0}, a1 = {0,0,0,0}, a2 = {0,0,0,0}, a3 = {0,0,0,0};
  const _Float16* Ap = A + (size_t)(m0 + r) * H + q * 8;
  const _Float16* Bp = Bt + (size_t)(nb + r) * H + q * 8;
  for (int k0 = 0; k0 < H; k0 += 32) {
    half8 a  = *(const half8*)(Ap + k0);
    half8 b0 = *(const half8*)(Bp + k0);
    half8 b1v = *(const half8*)(Bp + 16 * H + k0);
    half8 b2v = *(const half8*)(Bp + 32 * H + k0);
    half8 b3v = *(const half8*)(Bp + 48 * H + k0);
    a0 = __builtin_amdgcn_mfma_f32_16x16x32_f16(a, b0, a0, 0, 0, 0);
    a1 = __builtin_amdgcn_mfma_f32_16x16x32_f16(a, b1v, a1, 0, 0, 0);
    a2 = __builtin_amdgcn_mfma_f32_16x16x32_f16(a, b2v, a2, 0, 0, 0);
    a3 = __builtin_amdgcn_mfma_f32_16x16x32_f16(a, b3v, a3, 0, 0, 0);
  }
  floatx4 accs[4] = {a0, a1, a2, a3};
  #pragma unroll
  for (int nn = 0; nn < 4; nn++) {
    #pragma unroll
    for (int rr = 0; rr < 4; rr++) {
      int row = q * 4 + rr;
      int n = nb + nn * 16 + r;
      Cc[(size_t)(m0 + row) * F + n] = (_Float16)accs[nn][rr];
    }
  }
}

// ---------- layer-2 aggregation + bias + relu + per-wave max ----------
__global__ __launch_bounds__(256) void agg2_k(const _Float16* __restrict__ xw2,
                                              const int* __restrict__ offs,
                                              const int* __restrict__ csr,
                                              const float* __restrict__ dinv,
                                              const float* __restrict__ b2,
                                              float* __restrict__ partial, int N) {
  int lane = threadIdx.x & 63;
  int w = threadIdx.x >> 6;
  int nwaves = (gridDim.x * blockDim.x) >> 6;
  int gw = blockIdx.x * (blockDim.x >> 6) + w;
  int f0 = lane * 4;
  floatx4 bb = *(const floatx4*)(b2 + f0);
  floatx4 lmax = {0.f, 0.f, 0.f, 0.f};
  for (int node = gw; node < N; node += nwaves) {
    int beg = offs[node], end = offs[node + 1];
    float di = dinv[node];
    floatx4 acc = {0.f, 0.f, 0.f, 0.f};
    for (int c = beg; c < end; c += 64) {
      int m = min(64, end - c);
      int sv = 0; float wv = 0.f;
      if (lane < m) { sv = csr[c + lane]; wv = dinv[sv]; }
      #pragma unroll 4
      for (int j = 0; j < m; j++) {
        int sj = __shfl(sv, j, 64);
        float wj = __shfl(wv, j, 64);
        floatx4 xv = __builtin_convertvector(
            *(const half4*)(xw2 + (size_t)sj * F + f0), floatx4);
        acc += wj * xv;
      }
    }
    floatx4 xs = __builtin_convertvector(
        *(const half4*)(xw2 + (size_t)node * F + f0), floatx4);
    floatx4 v = di * acc + (di * di) * xs + bb;
    #pragma unroll
    for (int t = 0; t < 4; t++) lmax[t] = fmaxf(lmax[t], fmaxf(v[t], 0.f));
  }
  *(floatx4*)(partial + (size_t)gw * F + f0) = lmax;
}

__global__ __launch_bounds__(256) void maxred_k(const float* __restrict__ partial,
                                                float* __restrict__ out, int nrows) {
  int f = threadIdx.x;
  float lm = 0.f;
  for (int r = blockIdx.x; r < nrows; r += gridDim.x)
    lm = fmaxf(lm, partial[(size_t)r * F + f]);
  // relu outputs are >= 0, so int-punned max is order-correct; out pre-zeroed
  atomicMax((int*)&out[f], __float_as_int(lm));
}

extern "C" void kernel_launch(void* const* d_in, const int* in_sizes, int n_in,
                              void* d_out, int out_size, void* d_ws, size_t ws_size,
                              hipStream_t stream) {
  const float* x  = (const float*)d_in[0];
  const int*   ei = (const int*)d_in[1];
  const float* W1 = (const float*)d_in[2];
  const float* b1 = (const float*)d_in[3];
  const float* W2 = (const float*)d_in[4];
  const float* b2 = (const float*)d_in[5];
  const int E = in_sizes[1] / 2;
  const int N = NNODES;
  const int* src = ei;
  const int* dst = ei + E;

  char* w = (char*)d_ws;
  size_t off = 0;
  auto take = [&](size_t bytes) -> void* {
    void* p = w + off;
    off += (bytes + 255) & ~(size_t)255;
    return p;
  };
  int*       cnt    = (int*)take((size_t)N * 4);
  int*       offs   = (int*)take((size_t)(N + 1) * 4);
  int*       cursor = (int*)take((size_t)N * 4);
  float*     dinv   = (float*)take((size_t)N * 4);
  int*       csr    = (int*)take((size_t)E * 4);
  _Float16*  W1t    = (_Float16*)take((size_t)H * F * 2);
  _Float16*  W2t    = (_Float16*)take((size_t)F * H * 2);
  _Float16*  axh    = (_Float16*)take((size_t)N * F * 2);
  _Float16*  h1h    = (_Float16*)take((size_t)N * H * 2);
  _Float16*  xw2h   = (_Float16*)take((size_t)N * F * 2);
  const int AGG2_BLOCKS = 640;                    // 2560 waves
  const int AGG2_WAVES = AGG2_BLOCKS * 4;
  float*     partial = (float*)take((size_t)AGG2_WAVES * F * 4);

  hipMemsetAsync(cnt, 0, (size_t)N * 4, stream);
  hipMemsetAsync(cursor, 0, (size_t)N * 4, stream);
  hipMemsetAsync(d_out, 0, (size_t)out_size * 4, stream);

  count_k<<<(E + 255) / 256, 256, 0, stream>>>(dst, cnt, E);
  scan_k<<<1, 1024, 0, stream>>>(cnt, offs, dinv, N);
  fill_k<<<(E + 255) / 256, 256, 0, stream>>>(src, dst, offs, cursor, csr, E);
  convw_k<<<(F * H + 255) / 256, 256, 0, stream>>>(W1, W1t, F, H);
  convw_k<<<(F * H + 255) / 256, 256, 0, stream>>>(W2, W2t, H, F);
  agg1_k<<<2500, 256, 0, stream>>>(x, offs, csr, dinv, axh, N);   // 10000 waves
  gemm1_k<<<dim3(N / 16, 2), 256, 0, stream>>>(axh, W1t, b1, h1h);
  gemm2_k<<<N / 16, 256, 0, stream>>>(h1h, W2t, xw2h);
  agg2_k<<<AGG2_BLOCKS, 256, 0, stream>>>(xw2h, offs, csr, dinv, b2, partial, N);
  maxred_k<<<32, 256, 0, stream>>>(partial, (float*)d_out, AGG2_WAVES);
}

// Round 3
// 257.915 us; speedup vs baseline: 1.1572x; 1.1572x over previous
//
#include <hip/hip_runtime.h>

#define NNODES 10000
#define F 256
#define H 512

typedef _Float16 half8 __attribute__((ext_vector_type(8)));
typedef _Float16 half4 __attribute__((ext_vector_type(4)));
typedef float floatx4 __attribute__((ext_vector_type(4)));
typedef float floatx8 __attribute__((ext_vector_type(8)));

// ---------- CSR build ----------
__global__ __launch_bounds__(256) void count_k(const int* __restrict__ dst,
                                               int* __restrict__ cnt, int E) {
  int e = blockIdx.x * blockDim.x + threadIdx.x;
  if (e < E) atomicAdd(&cnt[dst[e]], 1);
}

// wave-shuffle scan: 1024 threads, 16 waves
__global__ __launch_bounds__(1024) void scan_k(const int* __restrict__ cnt,
                                               int* __restrict__ offs,
                                               float* __restrict__ dinv, int N) {
  __shared__ int wsum[16];
  __shared__ int carry_s;
  int tid = threadIdx.x, lane = tid & 63, w = tid >> 6;
  if (tid == 0) carry_s = 0;
  __syncthreads();
  for (int base = 0; base < N; base += 1024) {
    int i = base + tid;
    int v = (i < N) ? cnt[i] : 0;
    int s = v;
    #pragma unroll
    for (int o = 1; o < 64; o <<= 1) {
      int t = __shfl_up(s, o, 64);
      if (lane >= o) s += t;
    }
    if (lane == 63) wsum[w] = s;
    __syncthreads();
    if (w == 0 && lane < 16) {
      int t = wsum[lane];
      #pragma unroll
      for (int o = 1; o < 16; o <<= 1) {
        int u = __shfl_up(t, o, 64);
        if (lane >= o) t += u;
      }
      wsum[lane] = t;
    }
    __syncthreads();
    int wprefix = (w == 0) ? 0 : wsum[w - 1];
    int carry = carry_s;
    int incl = carry + wprefix + s;
    if (i < N) {
      offs[i] = incl - v;                  // exclusive prefix
      dinv[i] = rsqrtf((float)(v + 1));    // deg includes self-loop
    }
    __syncthreads();
    if (tid == 1023) carry_s = incl;
    __syncthreads();
  }
  if (tid == 0) offs[N] = carry_s;
}

// fill CSR; also precompute per-edge weight csrw[e] = dinv[src[e]]
__global__ __launch_bounds__(256) void fill_k(const int* __restrict__ src,
                                              const int* __restrict__ dst,
                                              const int* __restrict__ offs,
                                              const float* __restrict__ dinv,
                                              int* __restrict__ cursor,
                                              int* __restrict__ csr,
                                              float* __restrict__ csrw, int E) {
  int e = blockIdx.x * blockDim.x + threadIdx.x;
  if (e < E) {
    int d = dst[e];
    int s = src[e];
    int p = atomicAdd(&cursor[d], 1);
    int slot = offs[d] + p;
    csr[slot] = s;
    csrw[slot] = dinv[s];
  }
}

// ---------- weight transpose + f16 convert: W (K x Nc) -> Wt (Nc x K) ----------
__global__ __launch_bounds__(256) void convw_k(const float* __restrict__ W,
                                               _Float16* __restrict__ Wt,
                                               int K, int Nc) {
  int t = blockIdx.x * blockDim.x + threadIdx.x;
  if (t < Nc * K) {
    int n = t / K, k = t - n * K;
    Wt[t] = (_Float16)W[k * Nc + n];
  }
}

// ---------- fp32 -> f16 convert, 8 elems/thread ----------
__global__ __launch_bounds__(256) void convx_k(const float* __restrict__ x,
                                               _Float16* __restrict__ xh, int n8) {
  int t = blockIdx.x * blockDim.x + threadIdx.x;
  if (t < n8) {
    floatx8 v = *(const floatx8*)(x + (size_t)t * 8);
    *(half8*)(xh + (size_t)t * 8) = __builtin_convertvector(v, half8);
  }
}

// ---------- half-wave-per-node aggregation over f16 rows (F=256) ----------
// half-wave = 32 lanes x 8 f16 feats = one 512B row; 16B loads; unroll-8 ILP.
// FUSE_MAX=false: out = (D^-1/2 A D^-1/2) in  -> f16 rows
// FUSE_MAX=true : fused +bias, relu, per-halfwave feature max -> partial rows
template <bool FUSE_MAX>
__global__ __launch_bounds__(256) void aggh_k(const _Float16* __restrict__ in,
                                              const int* __restrict__ offs,
                                              const int* __restrict__ csr,
                                              const float* __restrict__ csrw,
                                              const float* __restrict__ dinv,
                                              const float* __restrict__ bias,
                                              _Float16* __restrict__ outh,
                                              float* __restrict__ partial, int N) {
  int lane = threadIdx.x & 63;
  int wvi = threadIdx.x >> 6;
  int half = lane >> 5;
  int hl = lane & 31;
  int f0 = hl * 8;
  int nhw = ((gridDim.x * blockDim.x) >> 6) * 2;
  int hw = (blockIdx.x * (blockDim.x >> 6) + wvi) * 2 + half;
  floatx8 bb = {};
  if (FUSE_MAX) bb = *(const floatx8*)(bias + f0);
  floatx8 lmax = {};
  for (int node = hw; node < N; node += nhw) {
    int beg = offs[node], end = offs[node + 1];
    float di = dinv[node];
    floatx8 acc = {};
    for (int c = beg; c < end; c += 32) {
      int m = min(32, end - c);
      int sv = 0; float wvv = 0.f;
      if (hl < m) { sv = csr[c + hl]; wvv = csrw[c + hl]; }
      int j = 0;
      for (; j + 8 <= m; j += 8) {
        #pragma unroll
        for (int u = 0; u < 8; u++) {
          int sj = __shfl(sv, (half << 5) | (j + u), 64);
          float wj = __shfl(wvv, (half << 5) | (j + u), 64);
          half8 hv = *(const half8*)(in + (size_t)sj * F + f0);
          acc += wj * __builtin_convertvector(hv, floatx8);
        }
      }
      for (; j < m; j++) {
        int sj = __shfl(sv, (half << 5) | j, 64);
        float wj = __shfl(wvv, (half << 5) | j, 64);
        half8 hv = *(const half8*)(in + (size_t)sj * F + f0);
        acc += wj * __builtin_convertvector(hv, floatx8);
      }
    }
    half8 xsv = *(const half8*)(in + (size_t)node * F + f0);
    floatx8 xs = __builtin_convertvector(xsv, floatx8);
    floatx8 tot = di * acc + (di * di) * xs;
    if (FUSE_MAX) {
      tot += bb;
      #pragma unroll
      for (int t = 0; t < 8; t++) lmax[t] = fmaxf(lmax[t], fmaxf(tot[t], 0.f));
    } else {
      *(half8*)(outh + (size_t)node * F + f0) = __builtin_convertvector(tot, half8);
    }
  }
  if (FUSE_MAX) *(floatx8*)(partial + (size_t)hw * F + f0) = lmax;
}

// ---------- GEMM1: (N x 256 f16) @ W1t (512 x 256 f16, n-major) -> relu(+b1) f16 ----------
__global__ __launch_bounds__(256) void gemm1_k(const _Float16* __restrict__ A,
                                               const _Float16* __restrict__ Bt,
                                               const float* __restrict__ bias,
                                               _Float16* __restrict__ Cc) {
  int lane = threadIdx.x & 63;
  int wv = threadIdx.x >> 6;
  int m0 = blockIdx.x * 16;
  int nb = blockIdx.y * 256 + wv * 64;
  int r = lane & 15, q = lane >> 4;
  floatx4 a0 = {0,0,0,0}, a1 = {0,0,0,0}, a2 = {0,0,0,0}, a3 = {0,0,0,0};
  const _Float16* Ap = A + (size_t)(m0 + r) * F + q * 8;
  const _Float16* Bp = Bt + (size_t)(nb + r) * F + q * 8;
  for (int k0 = 0; k0 < F; k0 += 32) {
    half8 a  = *(const half8*)(Ap + k0);
    half8 b0 = *(const half8*)(Bp + k0);
    half8 b1v = *(const half8*)(Bp + 16 * F + k0);
    half8 b2v = *(const half8*)(Bp + 32 * F + k0);
    half8 b3v = *(const half8*)(Bp + 48 * F + k0);
    a0 = __builtin_amdgcn_mfma_f32_16x16x32_f16(a, b0, a0, 0, 0, 0);
    a1 = __builtin_amdgcn_mfma_f32_16x16x32_f16(a, b1v, a1, 0, 0, 0);
    a2 = __builtin_amdgcn_mfma_f32_16x16x32_f16(a, b2v, a2, 0, 0, 0);
    a3 = __builtin_amdgcn_mfma_f32_16x16x32_f16(a, b3v, a3, 0, 0, 0);
  }
  floatx4 accs[4] = {a0, a1, a2, a3};
  #pragma unroll
  for (int nn = 0; nn < 4; nn++) {
    #pragma unroll
    for (int rr = 0; rr < 4; rr++) {
      int row = q * 4 + rr;
      int n = nb + nn * 16 + r;
      float v = accs[nn][rr] + bias[n];
      v = fmaxf(v, 0.f);
      Cc[(size_t)(m0 + row) * H + n] = (_Float16)v;
    }
  }
}

// ---------- GEMM2: (N x 512 f16) @ W2t (256 x 512 f16) -> xw2 f16 (no bias) ----------
__global__ __launch_bounds__(256) void gemm2_k(const _Float16* __restrict__ A,
                                               const _Float16* __restrict__ Bt,
                                               _Float16* __restrict__ Cc) {
  int lane = threadIdx.x & 63;
  int wv = threadIdx.x >> 6;
  int m0 = blockIdx.x * 16;
  int nb = wv * 64;
  int r = lane & 15, q = lane >> 4;
  floatx4 a0 = {0,0,0,0}, a1 = {0,0,0,0}, a2 = {0,0,0,0}, a3 = {0,0,0,0};
  const _Float16* Ap = A + (size_t)(m0 + r) * H + q * 8;
  const _Float16* Bp = Bt + (size_t)(nb + r) * H + q * 8;
  for (int k0 = 0; k0 < H; k0 += 32) {
    half8 a  = *(const half8*)(Ap + k0);
    half8 b0 = *(const half8*)(Bp + k0);
    half8 b1v = *(const half8*)(Bp + 16 * H + k0);
    half8 b2v = *(const half8*)(Bp + 32 * H + k0);
    half8 b3v = *(const half8*)(Bp + 48 * H + k0);
    a0 = __builtin_amdgcn_mfma_f32_16x16x32_f16(a, b0, a0, 0, 0, 0);
    a1 = __builtin_amdgcn_mfma_f32_16x16x32_f16(a, b1v, a1, 0, 0, 0);
    a2 = __builtin_amdgcn_mfma_f32_16x16x32_f16(a, b2v, a2, 0, 0, 0);
    a3 = __builtin_amdgcn_mfma_f32_16x16x32_f16(a, b3v, a3, 0, 0, 0);
  }
  floatx4 accs[4] = {a0, a1, a2, a3};
  #pragma unroll
  for (int nn = 0; nn < 4; nn++) {
    #pragma unroll
    for (int rr = 0; rr < 4; rr++) {
      int row = q * 4 + rr;
      int n = nb + nn * 16 + r;
      Cc[(size_t)(m0 + row) * F + n] = (_Float16)accs[nn][rr];
    }
  }
}

__global__ __launch_bounds__(256) void maxred_k(const float* __restrict__ partial,
                                                float* __restrict__ out, int nrows) {
  int f = threadIdx.x;
  float lm = 0.f;
  for (int r = blockIdx.x; r < nrows; r += gridDim.x)
    lm = fmaxf(lm, partial[(size_t)r * F + f]);
  // relu outputs are >= 0, so int-punned max is order-correct; out pre-zeroed
  atomicMax((int*)&out[f], __float_as_int(lm));
}

extern "C" void kernel_launch(void* const* d_in, const int* in_sizes, int n_in,
                              void* d_out, int out_size, void* d_ws, size_t ws_size,
                              hipStream_t stream) {
  const float* x  = (const float*)d_in[0];
  const int*   ei = (const int*)d_in[1];
  const float* W1 = (const float*)d_in[2];
  const float* b1 = (const float*)d_in[3];
  const float* W2 = (const float*)d_in[4];
  const float* b2 = (const float*)d_in[5];
  const int E = in_sizes[1] / 2;
  const int N = NNODES;
  const int* src = ei;
  const int* dst = ei + E;

  char* w = (char*)d_ws;
  size_t off = 0;
  auto take = [&](size_t bytes) -> void* {
    void* p = w + off;
    off += (bytes + 255) & ~(size_t)255;
    return p;
  };
  int*       cnt    = (int*)take((size_t)N * 4);
  int*       offs   = (int*)take((size_t)(N + 1) * 4);
  int*       cursor = (int*)take((size_t)N * 4);
  float*     dinv   = (float*)take((size_t)N * 4);
  int*       csr    = (int*)take((size_t)E * 4);
  float*     csrw   = (float*)take((size_t)E * 4);
  _Float16*  W1t    = (_Float16*)take((size_t)H * F * 2);
  _Float16*  W2t    = (_Float16*)take((size_t)F * H * 2);
  _Float16*  xh     = (_Float16*)take((size_t)N * F * 2);
  _Float16*  axh    = (_Float16*)take((size_t)N * F * 2);
  _Float16*  h1h    = (_Float16*)take((size_t)N * H * 2);
  _Float16*  xw2h   = (_Float16*)take((size_t)N * F * 2);
  const int AGG_BLOCKS = 1250;                 // 5000 waves = 10000 half-waves
  const int NHW = AGG_BLOCKS * 4 * 2;
  float*     partial = (float*)take((size_t)NHW * F * 4);

  hipMemsetAsync(cnt, 0, (size_t)N * 4, stream);
  hipMemsetAsync(cursor, 0, (size_t)N * 4, stream);
  hipMemsetAsync(d_out, 0, (size_t)out_size * 4, stream);

  count_k<<<(E + 255) / 256, 256, 0, stream>>>(dst, cnt, E);
  scan_k<<<1, 1024, 0, stream>>>(cnt, offs, dinv, N);
  fill_k<<<(E + 255) / 256, 256, 0, stream>>>(src, dst, offs, dinv, cursor, csr, csrw, E);
  convw_k<<<(F * H + 255) / 256, 256, 0, stream>>>(W1, W1t, F, H);
  convw_k<<<(F * H + 255) / 256, 256, 0, stream>>>(W2, W2t, H, F);
  convx_k<<<(N * F / 8 + 255) / 256, 256, 0, stream>>>(x, xh, N * F / 8);
  aggh_k<false><<<AGG_BLOCKS, 256, 0, stream>>>(xh, offs, csr, csrw, dinv,
                                                nullptr, axh, nullptr, N);
  gemm1_k<<<dim3(N / 16, 2), 256, 0, stream>>>(axh, W1t, b1, h1h);
  gemm2_k<<<N / 16, 256, 0, stream>>>(h1h, W2t, xw2h);
  aggh_k<true><<<AGG_BLOCKS, 256, 0, stream>>>(xw2h, offs, csr, csrw, dinv,
                                               b2, nullptr, partial, N);
  maxred_k<<<128, 256, 0, stream>>>(partial, (float*)d_out, NHW);
}

// Round 4
// 237.760 us; speedup vs baseline: 1.2553x; 1.0848x over previous
//
#include <hip/hip_runtime.h>

#define NNODES 10000
#define MP 10112            // NNODES padded to 79*128 for GEMM M-tiles
#define F 256
#define H 512

typedef _Float16 half8 __attribute__((ext_vector_type(8)));
typedef float floatx4 __attribute__((ext_vector_type(4)));
typedef float floatx8 __attribute__((ext_vector_type(8)));

// ---------- fused prep: zero cnt/cursor/out + W1^T + W2^T + x->f16 ----------
// blocks [0,80): zero; [80,592): W1t; [592,1104): W2t; [1104,2354): convx
__global__ __launch_bounds__(256) void prep_k(const float* __restrict__ W1,
                                              const float* __restrict__ W2,
                                              const float* __restrict__ x,
                                              _Float16* __restrict__ W1t,
                                              _Float16* __restrict__ W2t,
                                              _Float16* __restrict__ xh,
                                              int* __restrict__ cnt,
                                              int* __restrict__ cursor,
                                              float* __restrict__ out) {
  int b = blockIdx.x, tid = threadIdx.x;
  if (b < 80) {
    int idx = b * 256 + tid;
    if (idx < NNODES) cnt[idx] = 0;
    else if (idx < 2 * NNODES) cursor[idx - NNODES] = 0;
    else if (idx < 2 * NNODES + 256) out[idx - 2 * NNODES] = 0.f;
  } else if (b < 592) {
    int t = (b - 80) * 256 + tid;          // W1t (512x256): n=t>>8, k=t&255
    W1t[t] = (_Float16)W1[(t & 255) * 512 + (t >> 8)];
  } else if (b < 1104) {
    int t = (b - 592) * 256 + tid;         // W2t (256x512): n=t>>9, k=t&511
    W2t[t] = (_Float16)W2[(t & 511) * 256 + (t >> 9)];
  } else {
    int t = (b - 1104) * 256 + tid;        // 320000 threads, 8 floats each
    floatx8 v = *(const floatx8*)(x + (size_t)t * 8);
    *(half8*)(xh + (size_t)t * 8) = __builtin_convertvector(v, half8);
  }
}

// ---------- CSR build ----------
__global__ __launch_bounds__(256) void count_k(const int* __restrict__ dst,
                                               int* __restrict__ cnt, int E) {
  int e = blockIdx.x * blockDim.x + threadIdx.x;
  if (e < E) atomicAdd(&cnt[dst[e]], 1);
}

// single-pass scan: 1024 threads x 10 elems in registers, one global round-trip
__global__ __launch_bounds__(1024) void scan_k(const int* __restrict__ cnt,
                                               int* __restrict__ offs,
                                               float* __restrict__ dinv,
                                               int N, int E) {
  __shared__ int wsum[16];
  int tid = threadIdx.x, lane = tid & 63, w = tid >> 6;
  int base = tid * 10;
  int v[10];
  int local = 0;
  #pragma unroll
  for (int j = 0; j < 10; j++) {
    int i = base + j;
    v[j] = (i < N) ? cnt[i] : 0;
    local += v[j];
  }
  int s = local;
  #pragma unroll
  for (int o = 1; o < 64; o <<= 1) {
    int t = __shfl_up(s, o, 64);
    if (lane >= o) s += t;
  }
  if (lane == 63) wsum[w] = s;
  __syncthreads();
  if (w == 0 && lane < 16) {
    int t = wsum[lane];
    #pragma unroll
    for (int o = 1; o < 16; o <<= 1) {
      int u = __shfl_up(t, o, 64);
      if (lane >= o) t += u;
    }
    wsum[lane] = t;
  }
  __syncthreads();
  int prefix = ((w > 0) ? wsum[w - 1] : 0) + (s - local);  // exclusive
  #pragma unroll
  for (int j = 0; j < 10; j++) {
    int i = base + j;
    if (i < N) {
      offs[i] = prefix;
      dinv[i] = rsqrtf((float)(v[j] + 1));   // deg includes self-loop
      prefix += v[j];
    }
  }
  if (tid == 0) offs[N] = E;
}

// fill CSR; precompute per-edge weight csrw[e] = dinv[src[e]]
__global__ __launch_bounds__(256) void fill_k(const int* __restrict__ src,
                                              const int* __restrict__ dst,
                                              const int* __restrict__ offs,
                                              const float* __restrict__ dinv,
                                              int* __restrict__ cursor,
                                              int* __restrict__ csr,
                                              float* __restrict__ csrw, int E) {
  int e = blockIdx.x * blockDim.x + threadIdx.x;
  if (e < E) {
    int d = dst[e];
    int s = src[e];
    int p = atomicAdd(&cursor[d], 1);
    int slot = offs[d] + p;
    csr[slot] = s;
    csrw[slot] = dinv[s];
  }
}

// ---------- half-wave-per-node aggregation over f16 rows (F=256) ----------
template <bool FUSE_MAX>
__global__ __launch_bounds__(256) void aggh_k(const _Float16* __restrict__ in,
                                              const int* __restrict__ offs,
                                              const int* __restrict__ csr,
                                              const float* __restrict__ csrw,
                                              const float* __restrict__ dinv,
                                              const float* __restrict__ bias,
                                              _Float16* __restrict__ outh,
                                              float* __restrict__ partial, int N) {
  int lane = threadIdx.x & 63;
  int wvi = threadIdx.x >> 6;
  int half = lane >> 5;
  int hl = lane & 31;
  int f0 = hl * 8;
  int nhw = ((gridDim.x * blockDim.x) >> 6) * 2;
  int hw = (blockIdx.x * (blockDim.x >> 6) + wvi) * 2 + half;
  floatx8 bb = {};
  if (FUSE_MAX) bb = *(const floatx8*)(bias + f0);
  floatx8 lmax = {};
  for (int node = hw; node < N; node += nhw) {
    int beg = offs[node], end = offs[node + 1];
    float di = dinv[node];
    floatx8 acc = {};
    for (int c = beg; c < end; c += 32) {
      int m = min(32, end - c);
      int sv = 0; float wvv = 0.f;
      if (hl < m) { sv = csr[c + hl]; wvv = csrw[c + hl]; }
      int j = 0;
      for (; j + 8 <= m; j += 8) {
        #pragma unroll
        for (int u = 0; u < 8; u++) {
          int sj = __shfl(sv, (half << 5) | (j + u), 64);
          float wj = __shfl(wvv, (half << 5) | (j + u), 64);
          half8 hv = *(const half8*)(in + (size_t)sj * F + f0);
          acc += wj * __builtin_convertvector(hv, floatx8);
        }
      }
      for (; j < m; j++) {
        int sj = __shfl(sv, (half << 5) | j, 64);
        float wj = __shfl(wvv, (half << 5) | j, 64);
        half8 hv = *(const half8*)(in + (size_t)sj * F + f0);
        acc += wj * __builtin_convertvector(hv, floatx8);
      }
    }
    half8 xsv = *(const half8*)(in + (size_t)node * F + f0);
    floatx8 xs = __builtin_convertvector(xsv, floatx8);
    floatx8 tot = di * acc + (di * di) * xs;
    if (FUSE_MAX) {
      tot += bb;
      #pragma unroll
      for (int t = 0; t < 8; t++) lmax[t] = fmaxf(lmax[t], fmaxf(tot[t], 0.f));
    } else {
      *(half8*)(outh + (size_t)node * F + f0) = __builtin_convertvector(tot, half8);
    }
  }
  if (FUSE_MAX) *(floatx8*)(partial + (size_t)hw * F + f0) = lmax;
}

// ---------- tiled MFMA GEMM: C(MP x NT) = A(MP x K) @ Bt(NT x K)^T ----------
// wave tile 64 x (NJ*16); block = 2x2 waves = 128 x (NJ*32). Pad rows are
// finite garbage (0xAA) and only land in pad rows of padded buffers.
template <int K, int NT, int NJ, bool RELU>
__global__ __launch_bounds__(256) void gemm_k(const _Float16* __restrict__ A,
                                              const _Float16* __restrict__ Bt,
                                              const float* __restrict__ bias,
                                              _Float16* __restrict__ C) {
  int lane = threadIdx.x & 63;
  int wv = threadIdx.x >> 6;
  int r = lane & 15, q = lane >> 4;
  int m0 = blockIdx.x * 128 + (wv & 1) * 64;
  int n0 = blockIdx.y * (2 * NJ * 16) + (wv >> 1) * (NJ * 16);
  floatx4 acc[4][NJ] = {};
  const _Float16* Ap = A + (size_t)(m0 + r) * K + q * 8;
  const _Float16* Bp = Bt + (size_t)(n0 + r) * K + q * 8;
  for (int k0 = 0; k0 < K; k0 += 32) {
    half8 a[4], b[NJ];
    #pragma unroll
    for (int i = 0; i < 4; i++) a[i] = *(const half8*)(Ap + (size_t)i * 16 * K + k0);
    #pragma unroll
    for (int j = 0; j < NJ; j++) b[j] = *(const half8*)(Bp + (size_t)j * 16 * K + k0);
    #pragma unroll
    for (int i = 0; i < 4; i++)
      #pragma unroll
      for (int j = 0; j < NJ; j++)
        acc[i][j] = __builtin_amdgcn_mfma_f32_16x16x32_f16(a[i], b[j], acc[i][j], 0, 0, 0);
  }
  #pragma unroll
  for (int i = 0; i < 4; i++) {
    #pragma unroll
    for (int j = 0; j < NJ; j++) {
      int n = n0 + j * 16 + r;
      float bv = RELU ? bias[n] : 0.f;
      #pragma unroll
      for (int rr = 0; rr < 4; rr++) {
        int row = m0 + i * 16 + q * 4 + rr;
        float v = acc[i][j][rr] + bv;
        if (RELU) v = fmaxf(v, 0.f);
        C[(size_t)row * NT + n] = (_Float16)v;
      }
    }
  }
}

__global__ __launch_bounds__(256) void maxred_k(const float* __restrict__ partial,
                                                float* __restrict__ out, int nrows) {
  int f = threadIdx.x;
  float lm = 0.f;
  for (int r = blockIdx.x; r < nrows; r += gridDim.x)
    lm = fmaxf(lm, partial[(size_t)r * F + f]);
  // relu outputs >= 0 -> int-punned max is order-correct; out pre-zeroed
  atomicMax((int*)&out[f], __float_as_int(lm));
}

extern "C" void kernel_launch(void* const* d_in, const int* in_sizes, int n_in,
                              void* d_out, int out_size, void* d_ws, size_t ws_size,
                              hipStream_t stream) {
  const float* x  = (const float*)d_in[0];
  const int*   ei = (const int*)d_in[1];
  const float* W1 = (const float*)d_in[2];
  const float* b1 = (const float*)d_in[3];
  const float* W2 = (const float*)d_in[4];
  const float* b2 = (const float*)d_in[5];
  const int E = in_sizes[1] / 2;
  const int N = NNODES;
  const int* src = ei;
  const int* dst = ei + E;

  char* w = (char*)d_ws;
  size_t off = 0;
  auto take = [&](size_t bytes) -> void* {
    void* p = w + off;
    off += (bytes + 255) & ~(size_t)255;
    return p;
  };
  int*       cnt    = (int*)take((size_t)N * 4);
  int*       offs   = (int*)take((size_t)(N + 1) * 4);
  int*       cursor = (int*)take((size_t)N * 4);
  float*     dinv   = (float*)take((size_t)N * 4);
  int*       csr    = (int*)take((size_t)E * 4);
  float*     csrw   = (float*)take((size_t)E * 4);
  _Float16*  W1t    = (_Float16*)take((size_t)H * F * 2);
  _Float16*  W2t    = (_Float16*)take((size_t)F * H * 2);
  _Float16*  xh     = (_Float16*)take((size_t)N * F * 2);
  _Float16*  axh    = (_Float16*)take((size_t)MP * F * 2);   // padded M
  _Float16*  h1h    = (_Float16*)take((size_t)MP * H * 2);   // padded M
  _Float16*  xw2h   = (_Float16*)take((size_t)MP * F * 2);   // padded M
  const int AGG_BLOCKS = 1250;                 // 10000 half-waves = 1 node each
  const int NHW = AGG_BLOCKS * 4 * 2;
  float*     partial = (float*)take((size_t)NHW * F * 4);

  prep_k<<<2354, 256, 0, stream>>>(W1, W2, x, W1t, W2t, xh, cnt, cursor,
                                   (float*)d_out);
  count_k<<<(E + 255) / 256, 256, 0, stream>>>(dst, cnt, E);
  scan_k<<<1, 1024, 0, stream>>>(cnt, offs, dinv, N, E);
  fill_k<<<(E + 255) / 256, 256, 0, stream>>>(src, dst, offs, dinv, cursor, csr, csrw, E);
  aggh_k<false><<<AGG_BLOCKS, 256, 0, stream>>>(xh, offs, csr, csrw, dinv,
                                                nullptr, axh, nullptr, N);
  gemm_k<F, H, 4, true><<<dim3(MP / 128, 4), 256, 0, stream>>>(axh, W1t, b1, h1h);
  gemm_k<H, F, 2, false><<<dim3(MP / 128, 4), 256, 0, stream>>>(h1h, W2t, nullptr, xw2h);
  aggh_k<true><<<AGG_BLOCKS, 256, 0, stream>>>(xw2h, offs, csr, csrw, dinv,
                                               b2, nullptr, partial, N);
  maxred_k<<<128, 256, 0, stream>>>(partial, (float*)d_out, NHW);
}